// Round 6
// baseline (57.179 us; speedup 1.0000x reference)
//
#include <hip/hip_runtime.h>

// PDE2DReservoir — spectral Green's function, SINGLE dispatch with a
// hand-rolled grid barrier.
// measured[m] = sum_j vals_j * K(m - p_j); K is a fixed 127-radius stencil
// computed on a 128-periodic domain via folded cosine modes (wx,wy in 0..64):
//   lambda = 0.9 + 0.05*(cos wx + cos wy);  Khat = DT * sum_s f_s lambda^(63-s)
//   K(x,y) = sum_wx sum_wy W(wx)W(wy)/16384 * Khat * cos(wx x) cos(wy y)
// Barrier note (round-5 lesson): the POLL must bypass the per-XCD L2
// (system-scope atomic load -> sc0 sc1). An agent-scope relaxed load can be
// served from the local, non-coherent L2 and spin ~50us until eviction.

#define N_INJ   4096
#define N_MEAS  4096
#define ND      128
#define NM      65              // folded modes 0..64
#define STEPS   64
#define WRAP_M  4095
#define NB      256             // grid blocks (all co-resident: <=19KB LDS, 256 thr)
#define NT      256
#define MPB     16              // measurements per block

__device__ float    g_K[ND * ND];
__device__ float    g_vals[N_INJ];
__device__ int      g_pack[N_INJ];
__device__ unsigned g_bar = 0;   // monotonic arrive counter (replay-safe, no reset)

__global__ __launch_bounds__(NT) void fused(const float* __restrict__ u_t,
                                            const float* __restrict__ scales,
                                            const int* __restrict__ dims,
                                            const int* __restrict__ iix,
                                            const int* __restrict__ iiy,
                                            const int* __restrict__ mix,
                                            const int* __restrict__ miy,
                                            float* __restrict__ out) {
    const int b = blockIdx.x;
    const int t = threadIdx.x;

    __shared__ float ctab[ND];        // cos(2*pi*i/128)
    __shared__ float coeff[STEPS];    // DT * sin(2*pi*s/64)
    __shared__ float khf[NM * NM];    // weighted Khat, flat wx*65+wy (16.9 KB)
    __shared__ float Cw[NM];
    __shared__ int   smx[MPB], smy[MPB];
    __shared__ float part[4][MPB];

    // Measurement coords depend only on inputs — load before the barrier.
    if (t < MPB) { smx[t] = mix[b * MPB + t]; smy[t] = miy[b * MPB + t]; }

    // ---------------- Phase A: build (blocks 0..127: K row x=b) ----------------
    if (b < ND) {
        if (t < ND)    ctab[t]  = cosf(0.049087385212340517f * (float)t);
        if (t < STEPS) coeff[t] = 0.001f * sinf(0.09817477042468103f * (float)t);
        __syncthreads();

        // Horner over 17 table entries per thread: e = t + 256k
        float h[17], lam[17];
#pragma unroll
        for (int k = 0; k < 17; ++k) {
            int e = t + 256 * k; if (e > NM * NM - 1) e = NM * NM - 1;
            const int wx = e / NM, wy = e - wx * NM;
            lam[k] = 0.9f + 0.05f * (ctab[wx] + ctab[wy]);
            h[k]   = coeff[0];
        }
#pragma unroll 8
        for (int s = 1; s < STEPS; ++s) {
            const float cs = coeff[s];
#pragma unroll
            for (int k = 0; k < 17; ++k) h[k] = fmaf(h[k], lam[k], cs);
        }
#pragma unroll
        for (int k = 0; k < 17; ++k) {
            const int e = t + 256 * k;
            if (e < NM * NM) {
                const int wx = e / NM, wy = e - wx * NM;
                const float w = ((wx == 0 || wx == 64) ? 1.f : 2.f)
                              * ((wy == 0 || wy == 64) ? 1.f : 2.f) * (1.f / 16384.f);
                khf[e] = h[k] * w;
            }
        }
        __syncthreads();

        // Cw[wy] = sum_wx khf[wx][wy] * cos(wx * x)
        if (t < NM) {
            float acc = 0.f; int idx = 0;
#pragma unroll 5
            for (int wx = 0; wx < NM; ++wx) {
                acc = fmaf(khf[wx * NM + t], ctab[idx], acc);
                idx = (idx + b) & (ND - 1);
            }
            Cw[t] = acc;
        }
        __syncthreads();

        // K(x=b, y=t) = sum_wy Cw[wy] * cos(wy * y)
        if (t < ND) {
            float acc = 0.f; int idx = 0;
#pragma unroll 5
            for (int wy = 0; wy < NM; ++wy) {
                acc = fmaf(Cw[wy], ctab[idx], acc);
                idx = (idx + t) & (ND - 1);
            }
            g_K[b * ND + t] = acc;
        }
    } else if (b < ND + N_INJ / NT) {   // blocks 128..143: vals + packed coords
        const int j = (b - ND) * NT + t;
        g_vals[j] = scales[j] * u_t[dims[j]];
        g_pack[j] = (iix[j] << 12) | iiy[j];
    }

    // ---------------- Grid barrier (replay-safe, no reset) ----------------
    __threadfence();                     // release this block's writes
    __syncthreads();
    if (t == 0) {
        const unsigned old = __hip_atomic_fetch_add(&g_bar, 1u, __ATOMIC_ACQ_REL,
                                                    __HIP_MEMORY_SCOPE_AGENT);
        const unsigned target = (old & ~(unsigned)(NB - 1)) + NB;
        // SYSTEM-scope load: sc0 sc1 -> bypasses the stale per-XCD L2.
        while ((int)(__hip_atomic_load(&g_bar, __ATOMIC_RELAXED,
                                       __HIP_MEMORY_SCOPE_SYSTEM) - target) < 0)
            __builtin_amdgcn_s_sleep(2);
        __threadfence();                 // acquire: invalidate local caches
    }
    __syncthreads();

    // ---------------- Phase B: measure (all 256 blocks, 16 each) ----------------
    float acc[MPB];
#pragma unroll
    for (int i = 0; i < MPB; ++i) acc[i] = 0.f;

#pragma unroll
    for (int jj = 0; jj < N_INJ / NT; ++jj) {
        const int j   = jj * NT + t;
        const int p   = g_pack[j];
        const float v = g_vals[j];
        const int ix  = p >> 12;
        const int iy  = p & WRAP_M;
#pragma unroll
        for (int i = 0; i < MPB; ++i) {
            const int a  = (smx[i] - ix) & WRAP_M;
            const int c  = (smy[i] - iy) & WRAP_M;
            const int ax = a < 2048 ? a : 4096 - a;
            const int ay = c < 2048 ? c : 4096 - c;
            if (ax < 64 && ay < 64)
                acc[i] += v * g_K[((a & (ND - 1)) << 7) + (c & (ND - 1))];
        }
    }

#pragma unroll
    for (int i = 0; i < MPB; ++i) {
#pragma unroll
        for (int off = 32; off > 0; off >>= 1)
            acc[i] += __shfl_down(acc[i], off, 64);
    }
    const int lane = t & 63;
    const int wid  = t >> 6;
    if (lane == 0) {
#pragma unroll
        for (int i = 0; i < MPB; ++i) part[wid][i] = acc[i];
    }
    __syncthreads();
    if (t < MPB)
        out[b * MPB + t] = (part[0][t] + part[1][t]) + (part[2][t] + part[3][t]);
}

extern "C" void kernel_launch(void* const* d_in, const int* in_sizes, int n_in,
                              void* d_out, int out_size, void* d_ws, size_t ws_size,
                              hipStream_t stream) {
    const float* u_t        = (const float*)d_in[0];
    const float* inj_scales = (const float*)d_in[1];
    const int*   inj_dims   = (const int*)d_in[2];
    const int*   inj_ix     = (const int*)d_in[3];
    const int*   inj_iy     = (const int*)d_in[4];
    const int*   meas_ix    = (const int*)d_in[5];
    const int*   meas_iy    = (const int*)d_in[6];
    float*       out        = (float*)d_out;

    hipLaunchKernelGGL(fused, dim3(NB), dim3(NT), 0, stream,
                       u_t, inj_scales, inj_dims, inj_ix, inj_iy,
                       meas_ix, meas_iy, out);
}

// Round 7
// 28.139 us; speedup vs baseline: 2.0321x; 2.0321x over previous
//
#include <hip/hip_runtime.h>

// PDE2DReservoir — spectral Green's function, 2 dispatches, NO grid sync.
// measured[m] = sum_j vals_j * K(m - p_j); K = fixed 127-radius stencil,
// 128-periodic == free-space (support radius <= 63).
//   lambda(wx,wy) = 0.9 + 0.05*(cos tx + cos ty)
//   Khat = DT * sum_s f_s lambda^(63-s)            (Horner, deg 63)
//   BT[y][wx] = (1/16384) * sum_wy Khat cos(wy*y)  (pass 1, materialized)
//   K(x,y) = sum_wx BT[y][wx] cos(wx*x)            (pass 2: per-HIT dense dot
//                                                   in a dedicated phase)
// Round-4 lesson: the pass-2 dot is only slow when run divergently inside the
// scan (1-2 active lanes). Here: scan -> LDS hit list -> one thread per hit.
// Rounds 3/5/6 lesson: intra-kernel cross-XCD barriers cost ~50us; never again.

#define N_INJ   4096
#define N_MEAS  4096
#define ND      128
#define STEPS   64
#define WRAP_M  4095
#define MPB     16                   // measurements per block
#define MB      (N_MEAS / MPB)       // 256 measure blocks
#define HC      1024                 // hit-list capacity (expected ~63/block)

__device__ float g_BT[ND * ND];      // pass-1 output, transposed, /16384 folded
__device__ float g_vals[N_INJ];
__device__ int   g_pack[N_INJ];      // (ix<<12) | iy

// Blocks 0..127: Khat row wx=b (Horner) + pass-1 cosine transform -> g_BT.
// Blocks 128..159: vals + packed injection coords.
__global__ __launch_bounds__(128) void pass1_kernel(const float* __restrict__ u_t,
                                                    const float* __restrict__ scales,
                                                    const int* __restrict__ dims,
                                                    const int* __restrict__ iix,
                                                    const int* __restrict__ iiy) {
    const int b = blockIdx.x;
    const int t = threadIdx.x;
    if (b >= ND) {
        const int j = (b - ND) * 128 + t;       // 32 blocks * 128 = 4096
        g_vals[j] = scales[j] * u_t[dims[j]];
        g_pack[j] = (iix[j] << 12) | iiy[j];
        return;
    }
    __shared__ float ctab[ND];       // cos(2*pi*i/128)
    __shared__ float coeff[STEPS];   // DT * sin(2*pi*s/64)
    __shared__ float khat[ND];
    ctab[t] = cosf(0.049087385212340517f * (float)t);
    if (t < STEPS) coeff[t] = 0.001f * sinf(0.09817477042468103f * (float)t);
    __syncthreads();

    const float lam = 0.9f + 0.05f * (ctab[b] + ctab[t]);
    float h = coeff[0];
#pragma unroll 8
    for (int s = 1; s < STEPS; ++s) h = fmaf(h, lam, coeff[s]);
    khat[t] = h;                     // Khat(wx=b, wy=t)
    __syncthreads();

    float acc = 0.f;
#pragma unroll 8
    for (int wy = 0; wy < ND; ++wy)
        acc = fmaf(khat[wy], ctab[(wy * t) & (ND - 1)], acc);
    g_BT[t * ND + b] = acc * (1.f / 16384.f);   // transposed store
}

// 256 blocks x 256 threads; 16 measurements per block.
// Phase 1: scan all 4096 injections, append hits to an LDS list.
// Phase 2: one thread per hit computes the 128-term pass-2 dot densely.
__global__ __launch_bounds__(256) void measure_kernel(const int* __restrict__ mix,
                                                      const int* __restrict__ miy,
                                                      float* __restrict__ out) {
    const int b = blockIdx.x;
    const int t = threadIdx.x;
    __shared__ float ctab[ND];
    __shared__ int   hitP[HC];
    __shared__ float hitV[HC];
    __shared__ float smacc[MPB];
    __shared__ int   nhit;
    if (t < ND)  ctab[t]  = cosf(0.049087385212340517f * (float)t);
    if (t < MPB) smacc[t] = 0.f;
    if (t == 0)  nhit = 0;

    // block-uniform measurement coords -> scalar loads, registers
    int mx[MPB], my[MPB];
#pragma unroll
    for (int i = 0; i < MPB; ++i) {
        mx[i] = mix[b * MPB + i];
        my[i] = miy[b * MPB + i];
    }
    __syncthreads();

    // ---- Phase 1: scan ----
#pragma unroll 4
    for (int jj = 0; jj < N_INJ / 256; ++jj) {
        const int j   = jj * 256 + t;
        const int p   = g_pack[j];
        const float v = g_vals[j];
        const int ix  = p >> 12;
        const int iy  = p & WRAP_M;
#pragma unroll
        for (int i = 0; i < MPB; ++i) {
            const int a  = (mx[i] - ix) & WRAP_M;
            const int c  = (my[i] - iy) & WRAP_M;
            const int ax = min(a, 4096 - a);
            const int ay = min(c, 4096 - c);
            if (max(ax, ay) < 64) {
                const int pos = atomicAdd(&nhit, 1);
                if (pos < HC) {
                    hitP[pos] = ((a & 127) << 11) | ((c & 127) << 4) | i;
                    hitV[pos] = v;
                }
            }
        }
    }
    __syncthreads();

    // ---- Phase 2: dense per-hit dots (full lane utilization) ----
    const int nh = nhit < HC ? nhit : HC;
    for (int h = t; h < nh; h += 256) {
        const int pk   = hitP[h];
        const float v  = hitV[h];
        const int am   = pk >> 11;
        const int cm   = (pk >> 4) & 127;
        const int im   = pk & 15;
        const float4* __restrict__ Brow =
            reinterpret_cast<const float4*>(&g_BT[cm * ND]);
        // 4 independent chains: s_k = sum_q BT[4q+k]*cos((4q+k)*am)
        const int am4 = (am << 2) & 127;
        int i0 = 0, i1 = am, i2 = (2 * am) & 127, i3 = (3 * am) & 127;
        float s0 = 0.f, s1 = 0.f, s2 = 0.f, s3 = 0.f;
#pragma unroll 8
        for (int q = 0; q < 32; ++q) {
            const float4 bv = Brow[q];
            s0 = fmaf(bv.x, ctab[i0], s0); i0 = (i0 + am4) & 127;
            s1 = fmaf(bv.y, ctab[i1], s1); i1 = (i1 + am4) & 127;
            s2 = fmaf(bv.z, ctab[i2], s2); i2 = (i2 + am4) & 127;
            s3 = fmaf(bv.w, ctab[i3], s3); i3 = (i3 + am4) & 127;
        }
        atomicAdd(&smacc[im], v * ((s0 + s1) + (s2 + s3)));
    }
    __syncthreads();
    if (t < MPB) out[b * MPB + t] = smacc[t];
}

extern "C" void kernel_launch(void* const* d_in, const int* in_sizes, int n_in,
                              void* d_out, int out_size, void* d_ws, size_t ws_size,
                              hipStream_t stream) {
    const float* u_t        = (const float*)d_in[0];
    const float* inj_scales = (const float*)d_in[1];
    const int*   inj_dims   = (const int*)d_in[2];
    const int*   inj_ix     = (const int*)d_in[3];
    const int*   inj_iy     = (const int*)d_in[4];
    const int*   meas_ix    = (const int*)d_in[5];
    const int*   meas_iy    = (const int*)d_in[6];
    float*       out        = (float*)d_out;

    hipLaunchKernelGGL(pass1_kernel, dim3(ND + N_INJ / 128), dim3(128), 0, stream,
                       u_t, inj_scales, inj_dims, inj_ix, inj_iy);
    hipLaunchKernelGGL(measure_kernel, dim3(MB), dim3(256), 0, stream,
                       meas_ix, meas_iy, out);
}